// Round 1
// baseline (233.966 us; speedup 1.0000x reference)
//
#include <hip/hip_runtime.h>

// KvPageState: out = copy(kv_pages); out[dest] row <- [new_k[t], new_v[t]] for valid t.
//
// Shapes (fp32):
//   kv_pages   [1024, 64, 16, 128]  = 134,217,728 floats (512 MiB)
//   new_k      [8192, 8, 128]
//   new_v      [8192, 8, 128]
//   token_dests i32[8192], flat slot in [0, 65536), -1 (or OOB) = drop
//
// Each token writes one contiguous row of 2*8*128 = 2048 floats = 512 float4
// at byte offset dest * 8192. First 1024 floats come from new_k[t], next
// 1024 from new_v[t].

__global__ void kv_scatter_kernel(const float4* __restrict__ new_k,
                                  const float4* __restrict__ new_v,
                                  const int* __restrict__ dests,
                                  float4* __restrict__ out,
                                  int num_slots) {
    const int t = blockIdx.x;          // one block per token
    const int d = dests[t];
    if (d < 0 || d >= num_slots) return;   // pad / OOB -> dropped

    // 512 float4 per token row; 256 threads move 2 each (k half, v half).
    const float4* __restrict__ k = new_k + (size_t)t * 256;   // 256 float4 = 1024 floats
    const float4* __restrict__ v = new_v + (size_t)t * 256;
    float4* __restrict__ o = out + (size_t)d * 512;

    const int i = threadIdx.x;         // 0..255
    o[i]       = k[i];
    o[i + 256] = v[i];
}

extern "C" void kernel_launch(void* const* d_in, const int* in_sizes, int n_in,
                              void* d_out, int out_size, void* d_ws, size_t ws_size,
                              hipStream_t stream) {
    const float* kv_pages = (const float*)d_in[0];
    const float* new_k    = (const float*)d_in[1];
    const float* new_v    = (const float*)d_in[2];
    const int*   dests    = (const int*)d_in[3];

    const int num_tokens = in_sizes[3];                 // 8192
    const int row_floats = 2 * 8 * 128;                 // 2048
    const int num_slots  = out_size / row_floats;       // 65536

    // 1) bulk copy kv_pages -> out (512 MiB). Driver D2D copy, graph-capturable.
    hipMemcpyAsync(d_out, kv_pages, (size_t)out_size * sizeof(float),
                   hipMemcpyDeviceToDevice, stream);

    // 2) scatter token rows over the copy (stream-ordered after the memcpy).
    kv_scatter_kernel<<<num_tokens, 256, 0, stream>>>(
        (const float4*)new_k, (const float4*)new_v, dests,
        (float4*)d_out, num_slots);
}

// Round 2
// 201.644 us; speedup vs baseline: 1.1603x; 1.1603x over previous
//
#include <hip/hip_runtime.h>

// KvPageState fused: out[slot] <- (inv[slot]>=0 ? [new_k[t], new_v[t]] : kv_pages[slot])
//
// Shapes (fp32):
//   kv_pages   [1024, 64, 16, 128]  -> 65536 slot-rows of 2048 floats (8 KiB)
//   new_k/new_v [8192, 8, 128]      -> per-token 1024 floats each
//   token_dests i32[8192], flat slot in [0, 65536), -1/OOB = drop
//
// Inverse map (d_ws): inv[slot] = token writing that slot, else -1. Built
// fresh every call (deterministic, graph-safe). Destinations are distinct,
// so the scatter into inv is race-free.

typedef float f4 __attribute__((ext_vector_type(4)));

__global__ void inv_init_kernel(int* __restrict__ inv, int num_slots) {
    const int stride = gridDim.x * blockDim.x;
    for (int s = blockIdx.x * blockDim.x + threadIdx.x; s < num_slots; s += stride)
        inv[s] = -1;
}

__global__ void inv_scatter_kernel(const int* __restrict__ dests, int num_tokens,
                                   int* __restrict__ inv, int num_slots) {
    const int t = blockIdx.x * blockDim.x + threadIdx.x;
    if (t >= num_tokens) return;
    const int d = dests[t];
    if (d >= 0 && d < num_slots) inv[d] = t;
}

// One slot-row (512 float4) per block iteration; 256 threads x 2 float4.
// Branch is block-uniform (inv[slot] same for all threads in the iteration).
__global__ void fused_copy_scatter(const f4* __restrict__ kv_pages,
                                   const f4* __restrict__ new_k,
                                   const f4* __restrict__ new_v,
                                   const int* __restrict__ inv,
                                   f4* __restrict__ out,
                                   int num_slots) {
    const int i = threadIdx.x;  // 0..255
    for (int slot = blockIdx.x; slot < num_slots; slot += gridDim.x) {
        const int t = inv[slot];
        f4* o = out + (size_t)slot * 512;
        if (t >= 0) {
            const f4* k = new_k + (size_t)t * 256;
            const f4* v = new_v + (size_t)t * 256;
            __builtin_nontemporal_store(__builtin_nontemporal_load(k + i), o + i);
            __builtin_nontemporal_store(__builtin_nontemporal_load(v + i), o + i + 256);
        } else {
            const f4* src = kv_pages + (size_t)slot * 512;
            __builtin_nontemporal_store(__builtin_nontemporal_load(src + i), o + i);
            __builtin_nontemporal_store(__builtin_nontemporal_load(src + i + 256), o + i + 256);
        }
    }
}

// Fallback (ws too small): plain copy + overwrite scatter.
__global__ void kv_scatter_kernel(const f4* __restrict__ new_k,
                                  const f4* __restrict__ new_v,
                                  const int* __restrict__ dests,
                                  f4* __restrict__ out,
                                  int num_slots) {
    const int t = blockIdx.x;
    const int d = dests[t];
    if (d < 0 || d >= num_slots) return;
    const f4* k = new_k + (size_t)t * 256;
    const f4* v = new_v + (size_t)t * 256;
    f4* o = out + (size_t)d * 512;
    const int i = threadIdx.x;
    o[i]       = k[i];
    o[i + 256] = v[i];
}

extern "C" void kernel_launch(void* const* d_in, const int* in_sizes, int n_in,
                              void* d_out, int out_size, void* d_ws, size_t ws_size,
                              hipStream_t stream) {
    const float* kv_pages = (const float*)d_in[0];
    const float* new_k    = (const float*)d_in[1];
    const float* new_v    = (const float*)d_in[2];
    const int*   dests    = (const int*)d_in[3];

    const int num_tokens = in_sizes[3];                 // 8192
    const int row_floats = 2 * 8 * 128;                 // 2048
    const int num_slots  = out_size / row_floats;       // 65536

    if (ws_size >= (size_t)num_slots * sizeof(int)) {
        int* inv = (int*)d_ws;
        inv_init_kernel<<<256, 256, 0, stream>>>(inv, num_slots);
        inv_scatter_kernel<<<(num_tokens + 255) / 256, 256, 0, stream>>>(
            dests, num_tokens, inv, num_slots);
        fused_copy_scatter<<<2048, 256, 0, stream>>>(
            (const f4*)kv_pages, (const f4*)new_k, (const f4*)new_v,
            inv, (f4*)d_out, num_slots);
    } else {
        hipMemcpyAsync(d_out, kv_pages, (size_t)out_size * sizeof(float),
                       hipMemcpyDeviceToDevice, stream);
        kv_scatter_kernel<<<num_tokens, 256, 0, stream>>>(
            (const f4*)new_k, (const f4*)new_v, dests, (f4*)d_out, num_slots);
    }
}

// Round 3
// 197.147 us; speedup vs baseline: 1.1868x; 1.0228x over previous
//
#include <hip/hip_runtime.h>

// KvPageState fused, wave-per-row:
//   out[slot] <- (inv[slot]>=0 ? [new_k[t], new_v[t]] : kv_pages[slot])
//
// Shapes (fp32):
//   kv_pages    [1024, 64, 16, 128] -> 65536 slot-rows of 2048 floats (8 KiB)
//   new_k/new_v [8192, 8, 128]      -> per-token 1024 floats each
//   token_dests i32[8192], flat slot in [0, 65536), -1/OOB = drop
//
// inv (d_ws): inv[slot] = token writing that slot else -1, rebuilt every call
// (graph-safe, deterministic; dests are distinct -> race-free scatter).
//
// Each 64-lane wave owns one slot-row per iteration: 8x float4 per lane =
// 8 coalesced 1KiB wave-transactions, nontemporal both ways. inv for the
// NEXT iteration is prefetched so its latency hides under the data movement.

typedef float f4 __attribute__((ext_vector_type(4)));

__global__ void inv_init_kernel(int* __restrict__ inv, int num_slots) {
    const int stride = gridDim.x * blockDim.x;
    for (int s = blockIdx.x * blockDim.x + threadIdx.x; s < num_slots; s += stride)
        inv[s] = -1;
}

__global__ void inv_scatter_kernel(const int* __restrict__ dests, int num_tokens,
                                   int* __restrict__ inv, int num_slots) {
    const int t = blockIdx.x * blockDim.x + threadIdx.x;
    if (t >= num_tokens) return;
    const int d = dests[t];
    if (d >= 0 && d < num_slots) inv[d] = t;
}

__global__ void __launch_bounds__(256, 8)
fused_copy_scatter(const f4* __restrict__ kv_pages,
                   const f4* __restrict__ new_k,
                   const f4* __restrict__ new_v,
                   const int* __restrict__ inv,
                   f4* __restrict__ out,
                   int num_slots) {
    const int lane   = threadIdx.x & 63;
    const int wave   = blockIdx.x * (blockDim.x >> 6) + (threadIdx.x >> 6);
    const int nwaves = gridDim.x * (blockDim.x >> 6);

    int slot = wave;
    if (slot >= num_slots) return;
    int t = inv[slot];                       // wave-uniform

    for (; slot < num_slots; slot += nwaves) {
        const int nslot = slot + nwaves;
        const int tnext = (nslot < num_slots) ? inv[nslot] : -1;  // prefetch

        f4* o = out + (size_t)slot * 512 + lane;
        if (t >= 0) {
            const f4* k = new_k + (size_t)t * 256 + lane;
            const f4* v = new_v + (size_t)t * 256 + lane;
#pragma unroll
            for (int j = 0; j < 4; ++j)
                __builtin_nontemporal_store(__builtin_nontemporal_load(k + j * 64), o + j * 64);
#pragma unroll
            for (int j = 0; j < 4; ++j)
                __builtin_nontemporal_store(__builtin_nontemporal_load(v + j * 64), o + 256 + j * 64);
        } else {
            const f4* src = kv_pages + (size_t)slot * 512 + lane;
#pragma unroll
            for (int j = 0; j < 8; ++j)
                __builtin_nontemporal_store(__builtin_nontemporal_load(src + j * 64), o + j * 64);
        }
        t = tnext;
    }
}

// Fallback (ws too small): plain copy + overwrite scatter.
__global__ void kv_scatter_kernel(const f4* __restrict__ new_k,
                                  const f4* __restrict__ new_v,
                                  const int* __restrict__ dests,
                                  f4* __restrict__ out,
                                  int num_slots) {
    const int t = blockIdx.x;
    const int d = dests[t];
    if (d < 0 || d >= num_slots) return;
    const f4* k = new_k + (size_t)t * 256;
    const f4* v = new_v + (size_t)t * 256;
    f4* o = out + (size_t)d * 512;
    const int i = threadIdx.x;
    o[i]       = k[i];
    o[i + 256] = v[i];
}

extern "C" void kernel_launch(void* const* d_in, const int* in_sizes, int n_in,
                              void* d_out, int out_size, void* d_ws, size_t ws_size,
                              hipStream_t stream) {
    const float* kv_pages = (const float*)d_in[0];
    const float* new_k    = (const float*)d_in[1];
    const float* new_v    = (const float*)d_in[2];
    const int*   dests    = (const int*)d_in[3];

    const int num_tokens = in_sizes[3];                 // 8192
    const int row_floats = 2 * 8 * 128;                 // 2048
    const int num_slots  = out_size / row_floats;       // 65536

    if (ws_size >= (size_t)num_slots * sizeof(int)) {
        int* inv = (int*)d_ws;
        inv_init_kernel<<<256, 256, 0, stream>>>(inv, num_slots);
        inv_scatter_kernel<<<(num_tokens + 255) / 256, 256, 0, stream>>>(
            dests, num_tokens, inv, num_slots);
        // 2048 blocks x 256 thr = 8192 waves, fully resident (8 blk/CU);
        // 65536/8192 = 8 rows per wave.
        fused_copy_scatter<<<2048, 256, 0, stream>>>(
            (const f4*)kv_pages, (const f4*)new_k, (const f4*)new_v,
            inv, (f4*)d_out, num_slots);
    } else {
        hipMemcpyAsync(d_out, kv_pages, (size_t)out_size * sizeof(float),
                       hipMemcpyDeviceToDevice, stream);
        kv_scatter_kernel<<<num_tokens, 256, 0, stream>>>(
            (const f4*)new_k, (const f4*)new_v, dests, (f4*)d_out, num_slots);
    }
}